// Round 1
// baseline (1866.297 us; speedup 1.0000x reference)
//
#include <hip/hip_runtime.h>

#define B_ 2
#define S_ 512
#define F_ 4096
#define D_ 768
#define H_ 12

typedef __attribute__((ext_vector_type(8))) short bf16x8;
typedef __attribute__((ext_vector_type(4))) float f32x4;
typedef unsigned short u16;
typedef unsigned int u32;
typedef unsigned long long u64;

__device__ inline u16 f2bf(float f) {
  u32 u = __float_as_uint(f);
  u32 r = (u + 0x7fffu + ((u >> 16) & 1u)) >> 16;  // RNE
  return (u16)r;
}

__device__ inline void gload16(const void* g, void* l) {
  __builtin_amdgcn_global_load_lds((const __attribute__((address_space(1))) void*)g,
                                   (__attribute__((address_space(3))) void*)l, 16, 0, 0);
}

// ---------------- BT GEMM: C[M,N] = A[M,K] * B[N,K]^T, bf16 in, f32 acc -----------------
// 128x128 tile, BK=64, 4 waves (2x2), each wave 64x64 = 4x4 frags of 16x16x32 MFMA.
// SPLITK: z -> (b = z&1, s = z>>1); A += b*sAz + s*sKs; B += s*sKs; C += z*sCz.
template <typename OutT, bool MASK, bool ACC, bool SPLITK>
__global__ __launch_bounds__(256) void gemm_bt(
    const u16* __restrict__ A, long sAz, int lda,
    const u16* __restrict__ Bm, long sBz, int ldb,
    OutT* __restrict__ C, long sCz, int ldc,
    int K, long sKs, const u32* __restrict__ maskbits) {
  constexpr int BK = 64;
  __shared__ u16 sA[128 * BK];
  __shared__ u16 sB[128 * BK];
  const int z = blockIdx.z;
  if (SPLITK) {
    const int b = z & 1, s = z >> 1;
    A += (long)b * sAz + (long)s * sKs;
    Bm += (long)s * sKs;
    C += (long)z * sCz;
  } else {
    A += (long)z * sAz;
    Bm += (long)z * sBz;
    C += (long)z * sCz;
  }
  const int tm = blockIdx.y, tn = blockIdx.x;
  const int t = threadIdx.x;
  const int lane = t & 63, wave = t >> 6;
  const int wm = (wave >> 1) * 64, wn = (wave & 1) * 64;
  // staging: inst j, thread t covers LDS bytes (j*256+t)*16; row=(j*256+t)>>3, col=(t&7)*8
  const int srow = t >> 3, scol = (t & 7) * 8;
  const u16* Ag = A + (long)(tm * 128 + srow) * lda + scol;
  const u16* Bg = Bm + (long)(tn * 128 + srow) * ldb + scol;
  u16* lA = sA + t * 8;
  u16* lB = sB + t * 8;
  const int lr = lane & 15;
  const int lk = (lane >> 4) * 8;
  f32x4 acc[4][4] = {};
  const int nk = K / BK;
  for (int kt = 0; kt < nk; ++kt) {
    const u16* Agk = Ag + kt * BK;
    const u16* Bgk = Bg + kt * BK;
#pragma unroll
    for (int j = 0; j < 4; ++j) gload16(Agk + (long)j * 32 * lda, lA + j * 2048);
#pragma unroll
    for (int j = 0; j < 4; ++j) gload16(Bgk + (long)j * 32 * ldb, lB + j * 2048);
    __syncthreads();  // drains vmcnt(0) before barrier
#pragma unroll
    for (int kk = 0; kk < 2; ++kk) {
      bf16x8 af[4], bfr[4];
#pragma unroll
      for (int mi = 0; mi < 4; ++mi)
        af[mi] = *(const bf16x8*)&sA[(wm + mi * 16 + lr) * BK + kk * 32 + lk];
#pragma unroll
      for (int ni = 0; ni < 4; ++ni)
        bfr[ni] = *(const bf16x8*)&sB[(wn + ni * 16 + lr) * BK + kk * 32 + lk];
#pragma unroll
      for (int mi = 0; mi < 4; ++mi)
#pragma unroll
        for (int ni = 0; ni < 4; ++ni)
          acc[mi][ni] = __builtin_amdgcn_mfma_f32_16x16x32_bf16(af[mi], bfr[ni], acc[mi][ni], 0, 0, 0);
    }
    __syncthreads();
  }
  // epilogue: C row=(lane>>4)*4+reg, col=lane&15 (m89-verified layout)
  const int r0 = tm * 128 + wm + ((lane >> 4) << 2);
  const int c0 = tn * 128 + wn + lr;
#pragma unroll
  for (int mi = 0; mi < 4; ++mi) {
#pragma unroll
    for (int j = 0; j < 4; ++j) {
      const int row = r0 + mi * 16 + j;
#pragma unroll
      for (int ni = 0; ni < 4; ++ni) {
        const int col = c0 + ni * 16;
        float v = acc[mi][ni][j];
        if (MASK) {
          const u32 w = maskbits[row * (F_ / 32) + (col >> 5)];
          if (!((w >> (col & 31)) & 1u)) v = 0.0f;
        }
        const long idx = (long)row * ldc + col;
        if constexpr (ACC) {
          C[idx] += v;
        } else if constexpr (sizeof(OutT) == 2) {
          C[idx] = (OutT)f2bf(v);
        } else {
          C[idx] = (OutT)v;
        }
      }
    }
  }
}

// ---------------- prep kernels -----------------

// Detect mask element width: int32 {0,1} data has all-zero bytes at offsets %4 != 0.
__global__ void k_detect_mask(const unsigned char* __restrict__ m, int* flag) {
  __shared__ int s[256];
  const int t = threadIdx.x;
  int any = 0;
  for (int i = t; i < 65536; i += 256)
    if ((i & 3) && m[i]) any = 1;
  s[t] = any;
  __syncthreads();
  for (int w = 128; w > 0; w >>= 1) {
    if (t < w) s[t] |= s[t + w];
    __syncthreads();
  }
  if (t == 0) *flag = s[0];  // 1 => bytes (u8), 0 => int32
}

__global__ void k_pack_mask(const void* __restrict__ m, u64* __restrict__ bits,
                            const int* __restrict__ flag) {
  const long i = (long)blockIdx.x * 256 + threadIdx.x;
  const int u8mode = *flag;
  const int v = u8mode ? (int)((const unsigned char*)m)[i] : ((const int*)m)[i];
  const u64 b = __ballot(v != 0);
  if ((threadIdx.x & 63) == 0) bits[i >> 6] = b;
}

__global__ void k_cast_bf4(const float* __restrict__ in, u16* __restrict__ out, long n4) {
  const long i = (long)blockIdx.x * 256 + threadIdx.x;
  if (i < n4) {
    const float4 v = ((const float4*)in)[i];
    ushort4 o;
    o.x = f2bf(v.x); o.y = f2bf(v.y); o.z = f2bf(v.z); o.w = f2bf(v.w);
    ((ushort4*)out)[i] = o;
  }
}

// up_facts[b,k,g]/scale[b,k] -> out[b,g,k] (bf16), tiled transpose
__global__ void k_ln_transpose(const float* __restrict__ uf, const float* __restrict__ sc,
                               u16* __restrict__ out) {
  __shared__ float tile[32][33];
  const int b = blockIdx.z;
  const int g0 = blockIdx.x * 32, k0 = blockIdx.y * 32;
  const int x = threadIdx.x, y = threadIdx.y;
#pragma unroll
  for (int i = 0; i < 4; ++i) {
    const int k = k0 + y + i * 8;
    tile[y + i * 8][x] = uf[((long)(b * S_ + k)) * F_ + g0 + x] / sc[b * S_ + k];
  }
  __syncthreads();
#pragma unroll
  for (int i = 0; i < 4; ++i) {
    const int g = g0 + y + i * 8;
    out[((long)(b * F_ + g)) * S_ + k0 + x] = f2bf(tile[x][y + i * 8]);
  }
}

// in[R,C] f32 -> out[C,R] bf16
__global__ void k_transpose_cast(const float* __restrict__ in, u16* __restrict__ out, int R, int Cc) {
  __shared__ float tile[32][33];
  const int c0 = blockIdx.x * 32, r0 = blockIdx.y * 32;
  const int x = threadIdx.x, y = threadIdx.y;
#pragma unroll
  for (int i = 0; i < 4; ++i)
    tile[y + i * 8][x] = in[(long)(r0 + y + i * 8) * Cc + c0 + x];
  __syncthreads();
#pragma unroll
  for (int i = 0; i < 4; ++i)
    out[(long)(c0 + y + i * 8) * R + r0 + x] = f2bf(tile[x][y + i * 8]);
}

// out[j] = part[j] + part[n + j], j in [0, n) ; n = 2*S*F (split-K reduce)
__global__ void k_reduce_out(const float* __restrict__ part, float* __restrict__ out, long n) {
  const long i = (long)blockIdx.x * 256 + threadIdx.x;
  if (i < n / 4) {
    const float4 a = ((const float4*)part)[i];
    const float4 b = ((const float4*)(part + n))[i];
    float4 o;
    o.x = a.x + b.x; o.y = a.y + b.y; o.z = a.z + b.z; o.w = a.w + b.w;
    ((float4*)out)[i] = o;
  }
}

// ---------------- launch -----------------
extern "C" void kernel_launch(void* const* d_in, const int* in_sizes, int n_in,
                              void* d_out, int out_size, void* d_ws, size_t ws_size,
                              hipStream_t stream) {
  const float* up_facts = (const float*)d_in[0];
  const float* hook_scale = (const float*)d_in[1];
  const float* probs = (const float*)d_in[2];
  const float* down_enc = (const float*)d_in[3];
  const float* up_dec = (const float*)d_in[4];
  const float* w_ov = (const float*)d_in[5];
  const void* cmask = d_in[6];
  float* out = (float*)d_out;

  char* p = (char*)d_ws;
  auto take = [&](size_t bytes) -> char* {
    char* r = p;
    p += (bytes + 255) & ~(size_t)255;
    return r;
  };
  u16* probs_bf = (u16*)take((size_t)B_ * H_ * S_ * S_ * 2);  // 12.6 MB
  u16* upT_post = (u16*)take((size_t)B_ * F_ * S_ * 2);       //  8.4 MB  [b][g][k]
  u16* dE_bf    = (u16*)take((size_t)F_ * D_ * 2);            //  6.3 MB
  u16* wov_bf   = (u16*)take((size_t)H_ * D_ * D_ * 2);       // 14.2 MB
  u16* upT_dec  = (u16*)take((size_t)F_ * D_ * 2);            //  6.3 MB  [g][i]
  u16* tmp_buf  = (u16*)take((size_t)F_ * D_ * 2);            //  6.3 MB  per-h
  u16* vw_buf   = (u16*)take((size_t)F_ * F_ * 2);            // 33.6 MB  per-h
  u16* pup_buf  = (u16*)take((size_t)B_ * S_ * F_ * 2);       //  8.4 MB  per-h
  float* part   = (float*)take((size_t)4 * S_ * F_ * 4);      // 33.6 MB  [z=b+2s][S][F]
  u64* mbits    = (u64*)take((size_t)F_ * F_ / 8);            //  2.1 MB
  int* flag     = (int*)take(256);

  k_detect_mask<<<1, 256, 0, stream>>>((const unsigned char*)cmask, flag);
  k_pack_mask<<<(F_ * (long)F_) / 256, 256, 0, stream>>>(cmask, mbits, flag);
  k_cast_bf4<<<((long)B_ * H_ * S_ * S_ / 4 + 255) / 256, 256, 0, stream>>>(
      probs, probs_bf, (long)B_ * H_ * S_ * S_ / 4);
  k_cast_bf4<<<((long)F_ * D_ / 4 + 255) / 256, 256, 0, stream>>>(down_enc, dE_bf, (long)F_ * D_ / 4);
  k_cast_bf4<<<((long)H_ * D_ * D_ / 4 + 255) / 256, 256, 0, stream>>>(w_ov, wov_bf, (long)H_ * D_ * D_ / 4);
  k_ln_transpose<<<dim3(F_ / 32, S_ / 32, B_), dim3(32, 8), 0, stream>>>(up_facts, hook_scale, upT_post);
  k_transpose_cast<<<dim3(F_ / 32, D_ / 32, 1), dim3(32, 8), 0, stream>>>(up_dec, upT_dec, D_, F_);

  for (int h = 0; h < H_; ++h) {
    // G1: tmp[f,i] = dE[f,:] . W_OV[h,i,:]   (M=4096, N=768, K=768)
    gemm_bt<u16, false, false, false><<<dim3(D_ / 128, F_ / 128, 1), 256, 0, stream>>>(
        dE_bf, 0, D_, wov_bf + (long)h * D_ * D_, 0, D_, tmp_buf, 0, D_, D_, 0, nullptr);
    // G2: vw[f,g] = tmp[f,:] . upT_dec[g,:]  masked   (M=N=4096, K=768)
    gemm_bt<u16, true, false, false><<<dim3(F_ / 128, F_ / 128, 1), 256, 0, stream>>>(
        tmp_buf, 0, D_, upT_dec, 0, D_, vw_buf, 0, F_, D_, 0, (const u32*)mbits);
    // G3: pup[b][q,g] = probs[b,h][q,:] . upT_post[b][g,:]  (z=b, M=512, N=4096, K=512)
    gemm_bt<u16, false, false, false><<<dim3(F_ / 128, S_ / 128, B_), 256, 0, stream>>>(
        probs_bf + (long)h * S_ * S_, (long)H_ * S_ * S_, S_,
        upT_post, (long)F_ * S_, S_, pup_buf, (long)S_ * F_, F_, S_, 0, nullptr);
    // G4: part[b+2s][q,f] (+)= pup[b][q,:] . vw[f,:]  (split-K=2, z=4, M=512, N=4096, K=2048)
    if (h == 0)
      gemm_bt<float, false, false, true><<<dim3(F_ / 128, S_ / 128, 4), 256, 0, stream>>>(
          pup_buf, (long)S_ * F_, F_, vw_buf, 0, F_, part, (long)S_ * F_, F_, F_ / 2, (long)(F_ / 2), nullptr);
    else
      gemm_bt<float, false, true, true><<<dim3(F_ / 128, S_ / 128, 4), 256, 0, stream>>>(
          pup_buf, (long)S_ * F_, F_, vw_buf, 0, F_, part, (long)S_ * F_, F_, F_ / 2, (long)(F_ / 2), nullptr);
  }
  k_reduce_out<<<((long)2 * S_ * F_ / 4 + 255) / 256, 256, 0, stream>>>(part, out, (long)2 * S_ * F_);
}

// Round 2
// 1758.632 us; speedup vs baseline: 1.0612x; 1.0612x over previous
//
#include <hip/hip_runtime.h>

#define B_ 2
#define S_ 512
#define F_ 4096
#define D_ 768
#define H_ 12

typedef __attribute__((ext_vector_type(8))) short bf16x8;
typedef __attribute__((ext_vector_type(4))) float f32x4;
typedef unsigned short u16;
typedef unsigned int u32;
typedef unsigned long long u64;

__device__ inline u16 f2bf(float f) {
  u32 u = __float_as_uint(f);
  u32 r = (u + 0x7fffu + ((u >> 16) & 1u)) >> 16;  // RNE
  return (u16)r;
}

__device__ inline void gload16(const void* g, void* l) {
  __builtin_amdgcn_global_load_lds((const __attribute__((address_space(1))) void*)g,
                                   (__attribute__((address_space(3))) void*)l, 16, 0, 0);
}

// ---------------- BT GEMM: C[M,N] = A[M,K] * B[N,K]^T, bf16 in, f32 acc -----------------
// 128x128 tile, BK=64, 4 waves (2x2), each wave 64x64 = 4x4 frags of 16x16x32 MFMA.
// z decomposition: z1 = z/ZDIV, z0 = z%ZDIV; operand X += z1*sX1 + z0*sX0.
// SWAPXY: tm from blockIdx.x (so blocks sharing a B-panel are dispatch-adjacent).
template <typename OutT, bool MASK, bool ACC, int ZDIV, bool SWAPXY>
__global__ __launch_bounds__(256) void gemm_bt(
    const u16* __restrict__ A, long sA1, long sA0, int lda,
    const u16* __restrict__ Bm, long sB1, long sB0, int ldb,
    OutT* __restrict__ C, long sC1, long sC0, int ldc,
    int K, const u32* __restrict__ maskbits) {
  constexpr int BK = 64;
  __shared__ u16 sA[128 * BK];
  __shared__ u16 sB[128 * BK];
  const int z = blockIdx.z;
  const int z1 = z / ZDIV, z0 = z % ZDIV;
  A += z1 * sA1 + z0 * sA0;
  Bm += z1 * sB1 + z0 * sB0;
  C += z1 * sC1 + z0 * sC0;
  const int tm = SWAPXY ? blockIdx.x : blockIdx.y;
  const int tn = SWAPXY ? blockIdx.y : blockIdx.x;
  const int t = threadIdx.x;
  const int lane = t & 63, wave = t >> 6;
  const int wm = (wave >> 1) * 64, wn = (wave & 1) * 64;
  const int srow = t >> 3, scol = (t & 7) * 8;
  const u16* Ag = A + (long)(tm * 128 + srow) * lda + scol;
  const u16* Bg = Bm + (long)(tn * 128 + srow) * ldb + scol;
  u16* lA = sA + t * 8;
  u16* lB = sB + t * 8;
  const int lr = lane & 15;
  const int lk = (lane >> 4) * 8;
  f32x4 acc[4][4] = {};
  const int nk = K / BK;
  for (int kt = 0; kt < nk; ++kt) {
    const u16* Agk = Ag + kt * BK;
    const u16* Bgk = Bg + kt * BK;
#pragma unroll
    for (int j = 0; j < 4; ++j) gload16(Agk + (long)j * 32 * lda, lA + j * 2048);
#pragma unroll
    for (int j = 0; j < 4; ++j) gload16(Bgk + (long)j * 32 * ldb, lB + j * 2048);
    __syncthreads();  // drains vmcnt(0) before barrier
#pragma unroll
    for (int kk = 0; kk < 2; ++kk) {
      bf16x8 af[4], bfr[4];
#pragma unroll
      for (int mi = 0; mi < 4; ++mi)
        af[mi] = *(const bf16x8*)&sA[(wm + mi * 16 + lr) * BK + kk * 32 + lk];
#pragma unroll
      for (int ni = 0; ni < 4; ++ni)
        bfr[ni] = *(const bf16x8*)&sB[(wn + ni * 16 + lr) * BK + kk * 32 + lk];
#pragma unroll
      for (int mi = 0; mi < 4; ++mi)
#pragma unroll
        for (int ni = 0; ni < 4; ++ni)
          acc[mi][ni] = __builtin_amdgcn_mfma_f32_16x16x32_bf16(af[mi], bfr[ni], acc[mi][ni], 0, 0, 0);
    }
    __syncthreads();
  }
  // epilogue: C row=(lane>>4)*4+reg, col=lane&15 (m89-verified layout)
  const int r0 = tm * 128 + wm + ((lane >> 4) << 2);
  const int c0 = tn * 128 + wn + lr;
#pragma unroll
  for (int mi = 0; mi < 4; ++mi) {
#pragma unroll
    for (int j = 0; j < 4; ++j) {
      const int row = r0 + mi * 16 + j;
#pragma unroll
      for (int ni = 0; ni < 4; ++ni) {
        const int col = c0 + ni * 16;
        float v = acc[mi][ni][j];
        if (MASK) {
          const u32 w = maskbits[row * (F_ / 32) + (col >> 5)];
          if (!((w >> (col & 31)) & 1u)) v = 0.0f;
        }
        const long idx = (long)row * ldc + col;
        if constexpr (ACC) {
          C[idx] += v;
        } else if constexpr (sizeof(OutT) == 2) {
          C[idx] = (OutT)f2bf(v);
        } else {
          C[idx] = (OutT)v;
        }
      }
    }
  }
}

// ---------------- prep kernels -----------------

// Parallel mask-width detect: int32 {0,1} words have bytes 1..3 == 0.
// u8 mask words have nonzero high bytes with overwhelming probability in 64 KB.
__global__ void k_detect_mask(const u32* __restrict__ m, int* flag) {
  const int gid = blockIdx.x * 256 + threadIdx.x;  // 64 KB = 16384 words
  const u32 w = m[gid];
  const u64 b = __ballot((w & 0xFFFFFF00u) != 0u);
  if ((threadIdx.x & 63) == 0 && b) atomicOr(flag, 1);
}

__global__ void k_pack_mask(const void* __restrict__ m, u64* __restrict__ bits,
                            const int* __restrict__ flag) {
  const long i = (long)blockIdx.x * 256 + threadIdx.x;
  const int u8mode = *flag;
  const int v = u8mode ? (int)((const unsigned char*)m)[i] : ((const int*)m)[i];
  const u64 b = __ballot(v != 0);
  if ((threadIdx.x & 63) == 0) bits[i >> 6] = b;
}

__global__ void k_cast_bf4(const float* __restrict__ in, u16* __restrict__ out, long n4) {
  const long i = (long)blockIdx.x * 256 + threadIdx.x;
  if (i < n4) {
    const float4 v = ((const float4*)in)[i];
    ushort4 o;
    o.x = f2bf(v.x); o.y = f2bf(v.y); o.z = f2bf(v.z); o.w = f2bf(v.w);
    ((ushort4*)out)[i] = o;
  }
}

// up_facts[b,k,g]/scale[b,k] -> out[b,g,k] (bf16), tiled transpose
__global__ void k_ln_transpose(const float* __restrict__ uf, const float* __restrict__ sc,
                               u16* __restrict__ out) {
  __shared__ float tile[32][33];
  const int b = blockIdx.z;
  const int g0 = blockIdx.x * 32, k0 = blockIdx.y * 32;
  const int x = threadIdx.x, y = threadIdx.y;
#pragma unroll
  for (int i = 0; i < 4; ++i) {
    const int k = k0 + y + i * 8;
    tile[y + i * 8][x] = uf[((long)(b * S_ + k)) * F_ + g0 + x] / sc[b * S_ + k];
  }
  __syncthreads();
#pragma unroll
  for (int i = 0; i < 4; ++i) {
    const int g = g0 + y + i * 8;
    out[((long)(b * F_ + g)) * S_ + k0 + x] = f2bf(tile[x][y + i * 8]);
  }
}

// in[R,C] f32 -> out[C,R] bf16
__global__ void k_transpose_cast(const float* __restrict__ in, u16* __restrict__ out, int R, int Cc) {
  __shared__ float tile[32][33];
  const int c0 = blockIdx.x * 32, r0 = blockIdx.y * 32;
  const int x = threadIdx.x, y = threadIdx.y;
#pragma unroll
  for (int i = 0; i < 4; ++i)
    tile[y + i * 8][x] = in[(long)(r0 + y + i * 8) * Cc + c0 + x];
  __syncthreads();
#pragma unroll
  for (int i = 0; i < 4; ++i)
    out[(long)(c0 + y + i * 8) * R + r0 + x] = f2bf(tile[x][y + i * 8]);
}

// out[j] = sum_{s<ns} part[j + s*n], j in [0, n) ; n = 2*S*F
__global__ void k_reduce_out(const float* __restrict__ part, float* __restrict__ out,
                             long n, int ns) {
  const long i = (long)blockIdx.x * 256 + threadIdx.x;
  const long n4 = n / 4;
  if (i < n4) {
    float4 a = ((const float4*)part)[i];
    for (int s = 1; s < ns; ++s) {
      const float4 b = ((const float4*)part)[i + s * n4];
      a.x += b.x; a.y += b.y; a.z += b.z; a.w += b.w;
    }
    ((float4*)out)[i] = a;
  }
}

// ---------------- launch -----------------
extern "C" void kernel_launch(void* const* d_in, const int* in_sizes, int n_in,
                              void* d_out, int out_size, void* d_ws, size_t ws_size,
                              hipStream_t stream) {
  const float* up_facts = (const float*)d_in[0];
  const float* hook_scale = (const float*)d_in[1];
  const float* probs = (const float*)d_in[2];
  const float* down_enc = (const float*)d_in[3];
  const float* up_dec = (const float*)d_in[4];
  const float* w_ov = (const float*)d_in[5];
  const void* cmask = d_in[6];
  float* out = (float*)d_out;

  char* base = (char*)d_ws;
  size_t off = 0;
  auto al = [](size_t b) { return (b + 255) & ~(size_t)255; };
  auto take = [&](size_t bytes) -> char* { char* r = base + off; off += al(bytes); return r; };

  // fixed allocations (all tiers)
  u16* probs_bf = (u16*)take((size_t)B_ * H_ * S_ * S_ * 2);  // 12.6 MB
  u16* upT_post = (u16*)take((size_t)B_ * F_ * S_ * 2);       //  8.4 MB  [b][g][k]
  u16* dE_bf    = (u16*)take((size_t)F_ * D_ * 2);            //  6.3 MB
  u16* wov_bf   = (u16*)take((size_t)H_ * D_ * D_ * 2);       // 14.2 MB
  u16* upT_dec  = (u16*)take((size_t)F_ * D_ * 2);            //  6.3 MB  [g][i]
  u64* mbits    = (u64*)take((size_t)F_ * F_ / 8);            //  2.1 MB
  int* flag     = (int*)take(256);
  const size_t fixed_end = off;

  const size_t szTmpAll = (size_t)H_ * F_ * D_ * 2;       //  75.5 MB
  const size_t szVwAll  = (size_t)H_ * F_ * F_ * 2;       // 402.7 MB
  const size_t szPupAll = (size_t)B_ * S_ * H_ * F_ * 2;  // 100.7 MB
  const size_t szPart8  = (size_t)8 * S_ * F_ * 4;        //  67.1 MB
  const size_t szTmp1   = (size_t)F_ * D_ * 2;
  const size_t szVw1    = (size_t)F_ * F_ * 2;
  const size_t szPup1   = (size_t)B_ * S_ * F_ * 2;
  const size_t szPart4  = (size_t)4 * S_ * F_ * 4;

  const size_t needA = fixed_end + al(szTmpAll) + al(szVwAll) + al(szPupAll) + al(szPart8);
  const size_t needB = fixed_end + al(szTmpAll) + al(szVw1) + al(szPupAll) + al(szPart4);
  const int tier = (ws_size >= needA) ? 0 : (ws_size >= needB) ? 1 : 2;

  // ---- shared prep ----
  hipMemsetAsync(flag, 0, 4, stream);
  k_detect_mask<<<64, 256, 0, stream>>>((const u32*)cmask, flag);
  k_pack_mask<<<(F_ * (long)F_) / 256, 256, 0, stream>>>(cmask, mbits, flag);
  k_cast_bf4<<<((long)B_ * H_ * S_ * S_ / 4 + 255) / 256, 256, 0, stream>>>(
      probs, probs_bf, (long)B_ * H_ * S_ * S_ / 4);
  k_cast_bf4<<<((long)F_ * D_ / 4 + 255) / 256, 256, 0, stream>>>(down_enc, dE_bf, (long)F_ * D_ / 4);
  k_cast_bf4<<<((long)H_ * D_ * D_ / 4 + 255) / 256, 256, 0, stream>>>(w_ov, wov_bf, (long)H_ * D_ * D_ / 4);
  k_ln_transpose<<<dim3(F_ / 32, S_ / 32, B_), dim3(32, 8), 0, stream>>>(up_facts, hook_scale, upT_post);
  k_transpose_cast<<<dim3(F_ / 32, D_ / 32, 1), dim3(32, 8), 0, stream>>>(up_dec, upT_dec, D_, F_);

  const long n_out = (long)B_ * S_ * F_;  // 2*S*F

  if (tier == 0) {
    // ---------------- Tier A: fully batched ----------------
    u16* tmp_all = (u16*)take(szTmpAll);   // [h][f][i]
    u16* vw_all  = (u16*)take(szVwAll);    // [f][h*F+g]
    u16* pup_all = (u16*)take(szPupAll);   // [b][q][h][g]
    float* part  = (float*)take(szPart8);  // [s*2+b][q][f]

    // G1: tmp[h][f,i] = dE[f,:] . W_OV[h,i,:]   (z=h)
    gemm_bt<u16, false, false, 1, false><<<dim3(D_ / 128, F_ / 128, H_), 256, 0, stream>>>(
        dE_bf, 0, 0, D_, wov_bf, (long)D_ * D_, 0, D_,
        tmp_all, (long)F_ * D_, 0, D_, D_, nullptr);
    // G2: vw_all[f][h*F+g] = tmp[h][f,:] . upT_dec[g,:], masked  (z=h)
    gemm_bt<u16, true, false, 1, false><<<dim3(F_ / 128, F_ / 128, H_), 256, 0, stream>>>(
        tmp_all, (long)F_ * D_, 0, D_, upT_dec, 0, 0, D_,
        vw_all, (long)F_, 0, H_ * F_, D_, (const u32*)mbits);
    // G3: pup_all[b][q][h][g] = probs[b,h][q,:] . upT_post[b][g,:]  (z = h*2+b)
    gemm_bt<u16, false, false, 2, false><<<dim3(F_ / 128, S_ / 128, H_ * B_), 256, 0, stream>>>(
        probs_bf, (long)S_ * S_, (long)H_ * S_ * S_, S_,
        upT_post, 0, (long)F_ * S_, S_,
        pup_all, (long)F_, (long)S_ * H_ * F_, H_ * F_, S_, nullptr);
    // G4: one GEMM, K = H*F = 49152, split-K 4 (z = s*2+b), SWAPXY for B-panel adjacency
    const long sKs = (long)H_ * F_ / 4;  // 12288
    gemm_bt<float, false, false, 2, true><<<dim3(S_ / 128, F_ / 128, 8), 256, 0, stream>>>(
        pup_all, sKs, (long)S_ * H_ * F_, H_ * F_,
        vw_all, sKs, 0, H_ * F_,
        part, (long)2 * S_ * F_, (long)S_ * F_, F_, (int)sKs, nullptr);
    k_reduce_out<<<(n_out / 4 + 255) / 256, 256, 0, stream>>>(part, out, n_out, 4);
  } else if (tier == 1) {
    // ---------------- Tier B: batched G1/G3, per-head G2/G4 ----------------
    u16* tmp_all = (u16*)take(szTmpAll);
    u16* vw_buf  = (u16*)take(szVw1);
    u16* pup_all = (u16*)take(szPupAll);   // [b][q][h][g]
    float* part  = (float*)take(szPart4);

    gemm_bt<u16, false, false, 1, false><<<dim3(D_ / 128, F_ / 128, H_), 256, 0, stream>>>(
        dE_bf, 0, 0, D_, wov_bf, (long)D_ * D_, 0, D_,
        tmp_all, (long)F_ * D_, 0, D_, D_, nullptr);
    gemm_bt<u16, false, false, 2, false><<<dim3(F_ / 128, S_ / 128, H_ * B_), 256, 0, stream>>>(
        probs_bf, (long)S_ * S_, (long)H_ * S_ * S_, S_,
        upT_post, 0, (long)F_ * S_, S_,
        pup_all, (long)F_, (long)S_ * H_ * F_, H_ * F_, S_, nullptr);
    for (int h = 0; h < H_; ++h) {
      gemm_bt<u16, true, false, 1, false><<<dim3(F_ / 128, F_ / 128, 1), 256, 0, stream>>>(
          tmp_all + (long)h * F_ * D_, 0, 0, D_, upT_dec, 0, 0, D_,
          vw_buf, 0, 0, F_, D_, (const u32*)mbits);
      if (h == 0)
        gemm_bt<float, false, false, 2, false><<<dim3(F_ / 128, S_ / 128, 4), 256, 0, stream>>>(
            pup_all + (long)h * F_, (long)(F_ / 2), (long)S_ * H_ * F_, H_ * F_,
            vw_buf, (long)(F_ / 2), 0, F_,
            part, (long)2 * S_ * F_, (long)S_ * F_, F_, F_ / 2, nullptr);
      else
        gemm_bt<float, false, true, 2, false><<<dim3(F_ / 128, S_ / 128, 4), 256, 0, stream>>>(
            pup_all + (long)h * F_, (long)(F_ / 2), (long)S_ * H_ * F_, H_ * F_,
            vw_buf, (long)(F_ / 2), 0, F_,
            part, (long)2 * S_ * F_, (long)S_ * F_, F_, F_ / 2, nullptr);
    }
    k_reduce_out<<<(n_out / 4 + 255) / 256, 256, 0, stream>>>(part, out, n_out, 2);
  } else {
    // ---------------- Tier C: per-head everything (proven path) ----------------
    u16* tmp_buf = (u16*)take(szTmp1);
    u16* vw_buf  = (u16*)take(szVw1);
    u16* pup_buf = (u16*)take(szPup1);     // [b][q][g]
    float* part  = (float*)take(szPart4);

    for (int h = 0; h < H_; ++h) {
      gemm_bt<u16, false, false, 1, false><<<dim3(D_ / 128, F_ / 128, 1), 256, 0, stream>>>(
          dE_bf, 0, 0, D_, wov_bf + (long)h * D_ * D_, 0, 0, D_,
          tmp_buf, 0, 0, D_, D_, nullptr);
      gemm_bt<u16, true, false, 1, false><<<dim3(F_ / 128, F_ / 128, 1), 256, 0, stream>>>(
          tmp_buf, 0, 0, D_, upT_dec, 0, 0, D_,
          vw_buf, 0, 0, F_, D_, (const u32*)mbits);
      gemm_bt<u16, false, false, 1, false><<<dim3(F_ / 128, S_ / 128, B_), 256, 0, stream>>>(
          probs_bf + (long)h * S_ * S_, (long)H_ * S_ * S_, 0, S_,
          upT_post, (long)F_ * S_, 0, S_,
          pup_buf, (long)S_ * F_, 0, F_, S_, nullptr);
      if (h == 0)
        gemm_bt<float, false, false, 2, false><<<dim3(F_ / 128, S_ / 128, 4), 256, 0, stream>>>(
            pup_buf, (long)(F_ / 2), (long)S_ * F_, F_,
            vw_buf, (long)(F_ / 2), 0, F_,
            part, (long)2 * S_ * F_, (long)S_ * F_, F_, F_ / 2, nullptr);
      else
        gemm_bt<float, false, true, 2, false><<<dim3(F_ / 128, S_ / 128, 4), 256, 0, stream>>>(
            pup_buf, (long)(F_ / 2), (long)S_ * F_, F_,
            vw_buf, (long)(F_ / 2), 0, F_,
            part, (long)2 * S_ * F_, (long)S_ * F_, F_, F_ / 2, nullptr);
    }
    k_reduce_out<<<(n_out / 4 + 255) / 256, 256, 0, stream>>>(part, out, n_out, 2);
  }
}

// Round 3
// 1232.273 us; speedup vs baseline: 1.5145x; 1.4271x over previous
//
#include <hip/hip_runtime.h>

#define B_ 2
#define S_ 512
#define F_ 4096
#define D_ 768
#define H_ 12

typedef __attribute__((ext_vector_type(8))) short bf16x8;
typedef __attribute__((ext_vector_type(4))) float f32x4;
typedef unsigned short u16;
typedef unsigned int u32;
typedef unsigned long long u64;

__device__ inline u16 f2bf(float f) {
  u32 u = __float_as_uint(f);
  u32 r = (u + 0x7fffu + ((u >> 16) & 1u)) >> 16;  // RNE
  return (u16)r;
}

__device__ inline void gload16(const void* g, void* l) {
  __builtin_amdgcn_global_load_lds((const __attribute__((address_space(1))) void*)g,
                                   (__attribute__((address_space(3))) void*)l, 16, 0, 0);
}

// ---------------- BT GEMM: C[M,N] = A[M,K] * B[N,K]^T, bf16 in, f32 acc -----------------
// 128x128 tile, BK=64, 4 waves (2x2), each wave 64x64 = 4x4 frags of 16x16x32 MFMA.
// LDS XOR swizzle (rule #21): dest linear, source chunk ^= row&7, read chunk ^= row&7.
// XCD swizzle (T1/m204, bijective): per z-slice remap of (x,y) linear id.
// z decomposition: z1 = z/ZDIV, z0 = z%ZDIV; operand X += z1*sX1 + z0*sX0.
template <typename OutT, bool MASK, bool ACC, int ZDIV, bool TMFAST>
__global__ __launch_bounds__(256) void gemm_bt(
    const u16* __restrict__ A, long sA1, long sA0, int lda,
    const u16* __restrict__ Bm, long sB1, long sB0, int ldb,
    OutT* __restrict__ C, long sC1, long sC0, int ldc,
    int K, const u32* __restrict__ maskbits) {
  constexpr int BK = 64;
  __shared__ u16 sA[128 * BK];
  __shared__ u16 sB[128 * BK];
  const int z = blockIdx.z;
  const int z1 = z / ZDIV, z0 = z % ZDIV;
  A += z1 * sA1 + z0 * sA0;
  Bm += z1 * sB1 + z0 * sB0;
  C += z1 * sC1 + z0 * sC0;
  // XCD-aware bijective swizzle of the (x,y) tile id (m204)
  const int gx = gridDim.x, gy = gridDim.y;
  const int nwg = gx * gy;
  const int lin = blockIdx.y * gx + blockIdx.x;
  const int q8 = nwg >> 3, r8 = nwg & 7;
  const int xcd = lin & 7, idx = lin >> 3;
  const int swz = (xcd < r8 ? xcd * (q8 + 1) : r8 * (q8 + 1) + (xcd - r8) * q8) + idx;
  const int tm = TMFAST ? (swz % gy) : (swz / gx);
  const int tn = TMFAST ? (swz / gy) : (swz % gx);
  const int t = threadIdx.x;
  const int lane = t & 63, wave = t >> 6;
  const int wm = (wave >> 1) * 64, wn = (wave & 1) * 64;
  // staging: thread t covers LDS row (t>>3), 16B-chunk (t&7); source chunk XOR-swizzled
  const int srow = t >> 3;
  const int scol = (((t & 7) ^ (srow & 7))) * 8;
  const u16* Ag = A + (long)(tm * 128 + srow) * lda + scol;
  const u16* Bg = Bm + (long)(tn * 128 + srow) * ldb + scol;
  u16* lA = sA + t * 8;
  u16* lB = sB + t * 8;
  const int lr = lane & 15;
  const int hi = lane >> 4;
  const int x7 = lr & 7;
  f32x4 acc[4][4] = {};
  const int nk = K / BK;
  for (int kt = 0; kt < nk; ++kt) {
    const u16* Agk = Ag + kt * BK;
    const u16* Bgk = Bg + kt * BK;
#pragma unroll
    for (int j = 0; j < 4; ++j) gload16(Agk + (long)j * 32 * lda, lA + j * 2048);
#pragma unroll
    for (int j = 0; j < 4; ++j) gload16(Bgk + (long)j * 32 * ldb, lB + j * 2048);
    __syncthreads();  // drains vmcnt(0) before barrier
#pragma unroll
    for (int kk = 0; kk < 2; ++kk) {
      bf16x8 af[4], bfr[4];
#pragma unroll
      for (int mi = 0; mi < 4; ++mi)
        af[mi] = *(const bf16x8*)&sA[(wm + mi * 16 + lr) * BK + (((kk * 4 + hi) ^ x7) << 3)];
#pragma unroll
      for (int ni = 0; ni < 4; ++ni)
        bfr[ni] = *(const bf16x8*)&sB[(wn + ni * 16 + lr) * BK + (((kk * 4 + hi) ^ x7) << 3)];
#pragma unroll
      for (int mi = 0; mi < 4; ++mi)
#pragma unroll
        for (int ni = 0; ni < 4; ++ni)
          acc[mi][ni] = __builtin_amdgcn_mfma_f32_16x16x32_bf16(af[mi], bfr[ni], acc[mi][ni], 0, 0, 0);
    }
    __syncthreads();
  }
  // epilogue: C row=(lane>>4)*4+reg, col=lane&15 (m89-verified layout)
  const int r0 = tm * 128 + wm + (hi << 2);
  const int c0 = tn * 128 + wn + lr;
#pragma unroll
  for (int mi = 0; mi < 4; ++mi) {
#pragma unroll
    for (int j = 0; j < 4; ++j) {
      const int row = r0 + mi * 16 + j;
#pragma unroll
      for (int ni = 0; ni < 4; ++ni) {
        const int col = c0 + ni * 16;
        float v = acc[mi][ni][j];
        if (MASK) {
          const int g = col & (F_ - 1);  // local g within head slab (F power of 2)
          const u32 w = maskbits[row * (F_ / 32) + (g >> 5)];
          if (!((w >> (g & 31)) & 1u)) v = 0.0f;
        }
        const long idx = (long)row * ldc + col;
        if constexpr (ACC) {
          C[idx] += v;
        } else if constexpr (sizeof(OutT) == 2) {
          C[idx] = (OutT)f2bf(v);
        } else {
          C[idx] = (OutT)v;
        }
      }
    }
  }
}

// ---------------- prep kernels -----------------

// Parallel mask-width detect: int32 {0,1} words have bytes 1..3 == 0.
__global__ void k_detect_mask(const u32* __restrict__ m, int* flag) {
  const int gid = blockIdx.x * 256 + threadIdx.x;  // 64 KB = 16384 words
  const u32 w = m[gid];
  const u64 b = __ballot((w & 0xFFFFFF00u) != 0u);
  if ((threadIdx.x & 63) == 0 && b) atomicOr(flag, 1);
}

__global__ void k_pack_mask(const void* __restrict__ m, u64* __restrict__ bits,
                            const int* __restrict__ flag) {
  const long i = (long)blockIdx.x * 256 + threadIdx.x;
  const int u8mode = *flag;
  const int v = u8mode ? (int)((const unsigned char*)m)[i] : ((const int*)m)[i];
  const u64 b = __ballot(v != 0);
  if ((threadIdx.x & 63) == 0) bits[i >> 6] = b;
}

__global__ void k_cast_bf4(const float* __restrict__ in, u16* __restrict__ out, long n4) {
  const long i = (long)blockIdx.x * 256 + threadIdx.x;
  if (i < n4) {
    const float4 v = ((const float4*)in)[i];
    ushort4 o;
    o.x = f2bf(v.x); o.y = f2bf(v.y); o.z = f2bf(v.z); o.w = f2bf(v.w);
    ((ushort4*)out)[i] = o;
  }
}

// up_facts[b,k,g]/scale[b,k] -> out[b,g,k] (bf16), tiled transpose
__global__ void k_ln_transpose(const float* __restrict__ uf, const float* __restrict__ sc,
                               u16* __restrict__ out) {
  __shared__ float tile[32][33];
  const int b = blockIdx.z;
  const int g0 = blockIdx.x * 32, k0 = blockIdx.y * 32;
  const int x = threadIdx.x, y = threadIdx.y;
#pragma unroll
  for (int i = 0; i < 4; ++i) {
    const int k = k0 + y + i * 8;
    tile[y + i * 8][x] = uf[((long)(b * S_ + k)) * F_ + g0 + x] / sc[b * S_ + k];
  }
  __syncthreads();
#pragma unroll
  for (int i = 0; i < 4; ++i) {
    const int g = g0 + y + i * 8;
    out[((long)(b * F_ + g)) * S_ + k0 + x] = f2bf(tile[x][y + i * 8]);
  }
}

// in[R,C] f32 -> out[C,R] bf16
__global__ void k_transpose_cast(const float* __restrict__ in, u16* __restrict__ out, int R, int Cc) {
  __shared__ float tile[32][33];
  const int c0 = blockIdx.x * 32, r0 = blockIdx.y * 32;
  const int x = threadIdx.x, y = threadIdx.y;
#pragma unroll
  for (int i = 0; i < 4; ++i)
    tile[y + i * 8][x] = in[(long)(r0 + y + i * 8) * Cc + c0 + x];
  __syncthreads();
#pragma unroll
  for (int i = 0; i < 4; ++i)
    out[(long)(c0 + y + i * 8) * R + r0 + x] = f2bf(tile[x][y + i * 8]);
}

// out[j] = sum_{s<ns} part[j + s*n], j in [0, n)
__global__ void k_reduce_out(const float* __restrict__ part, float* __restrict__ out,
                             long n, int ns) {
  const long i = (long)blockIdx.x * 256 + threadIdx.x;
  const long n4 = n / 4;
  if (i < n4) {
    float4 a = ((const float4*)part)[i];
    for (int s = 1; s < ns; ++s) {
      const float4 b = ((const float4*)part)[i + s * n4];
      a.x += b.x; a.y += b.y; a.z += b.z; a.w += b.w;
    }
    ((float4*)out)[i] = a;
  }
}

// ---------------- launch -----------------
extern "C" void kernel_launch(void* const* d_in, const int* in_sizes, int n_in,
                              void* d_out, int out_size, void* d_ws, size_t ws_size,
                              hipStream_t stream) {
  const float* up_facts = (const float*)d_in[0];
  const float* hook_scale = (const float*)d_in[1];
  const float* probs = (const float*)d_in[2];
  const float* down_enc = (const float*)d_in[3];
  const float* up_dec = (const float*)d_in[4];
  const float* w_ov = (const float*)d_in[5];
  const void* cmask = d_in[6];
  float* out = (float*)d_out;

  char* base = (char*)d_ws;
  size_t off = 0;
  auto al = [](size_t b) { return (b + 255) & ~(size_t)255; };
  auto take = [&](size_t bytes) -> char* { char* r = base + off; off += al(bytes); return r; };

  // fixed allocations
  u16* probs_bf = (u16*)take((size_t)B_ * H_ * S_ * S_ * 2);  // 12.6 MB
  u16* upT_post = (u16*)take((size_t)B_ * F_ * S_ * 2);       //  8.4 MB  [b][g][k]
  u16* dE_bf    = (u16*)take((size_t)F_ * D_ * 2);            //  6.3 MB
  u16* wov_bf   = (u16*)take((size_t)H_ * D_ * D_ * 2);       // 14.2 MB
  u16* upT_dec  = (u16*)take((size_t)F_ * D_ * 2);            //  6.3 MB  [g][i]
  u64* mbits    = (u64*)take((size_t)F_ * F_ / 8);            //  2.1 MB
  int* flag     = (int*)take(256);
  const size_t fixed_end = off;

  // head-chunk size NH: largest of {4,3,2,1} that fits (deterministic in ws_size)
  int NH = 1;
  for (int cand = 4; cand >= 2; --cand) {
    if (H_ % cand) continue;
    const size_t need = fixed_end + al((size_t)cand * F_ * D_ * 2)      // tmp_c
                      + al((size_t)cand * F_ * F_ * 2)                  // vw_c
                      + al((size_t)B_ * S_ * cand * F_ * 2)             // pup_c
                      + al((size_t)4 * S_ * F_ * 4);                    // part
    if (ws_size >= need) { NH = cand; break; }
  }
  u16* tmp_c  = (u16*)take((size_t)NH * F_ * D_ * 2);       // [nh][f][i]
  u16* vw_c   = (u16*)take((size_t)NH * F_ * F_ * 2);       // [f][nh*F+g]
  u16* pup_c  = (u16*)take((size_t)B_ * S_ * NH * F_ * 2);  // [b][q][nh][g]
  float* part = (float*)take((size_t)4 * S_ * F_ * 4);      // [s*2+b][q][f]

  // ---- prep ----
  hipMemsetAsync(flag, 0, 4, stream);
  k_detect_mask<<<64, 256, 0, stream>>>((const u32*)cmask, flag);
  k_pack_mask<<<(F_ * (long)F_) / 256, 256, 0, stream>>>(cmask, mbits, flag);
  k_cast_bf4<<<((long)B_ * H_ * S_ * S_ / 4 + 255) / 256, 256, 0, stream>>>(
      probs, probs_bf, (long)B_ * H_ * S_ * S_ / 4);
  k_cast_bf4<<<((long)F_ * D_ / 4 + 255) / 256, 256, 0, stream>>>(down_enc, dE_bf, (long)F_ * D_ / 4);
  k_cast_bf4<<<((long)H_ * D_ * D_ / 4 + 255) / 256, 256, 0, stream>>>(w_ov, wov_bf, (long)H_ * D_ * D_ / 4);
  k_ln_transpose<<<dim3(F_ / 32, S_ / 32, B_), dim3(32, 8), 0, stream>>>(up_facts, hook_scale, upT_post);
  k_transpose_cast<<<dim3(F_ / 32, D_ / 32, 1), dim3(32, 8), 0, stream>>>(up_dec, upT_dec, D_, F_);

  const int ldK = NH * F_;  // K extent of the chunked G4 contraction
  for (int h0 = 0; h0 < H_; h0 += NH) {
    // G1: tmp_c[nh][f,i] = dE[f,:] . W_OV[h0+nh,i,:]   (z=nh)
    gemm_bt<u16, false, false, 1, false><<<dim3(D_ / 128, F_ / 128, NH), 256, 0, stream>>>(
        dE_bf, 0, 0, D_,
        wov_bf + (size_t)h0 * D_ * D_, (long)D_ * D_, 0, D_,
        tmp_c, (long)F_ * D_, 0, D_, D_, nullptr);
    // G2: vw_c[f][nh*F+g] = tmp_c[nh][f,:] . upT_dec[g,:], masked  (z=nh)
    gemm_bt<u16, true, false, 1, false><<<dim3(F_ / 128, F_ / 128, NH), 256, 0, stream>>>(
        tmp_c, (long)F_ * D_, 0, D_,
        upT_dec, 0, 0, D_,
        vw_c, (long)F_, 0, ldK, D_, (const u32*)mbits);
    // G3: pup_c[b][q][nh][g] = probs[b,h0+nh][q,:] . upT_post[b][g,:]  (z = nh*2+b)
    gemm_bt<u16, false, false, 2, false><<<dim3(F_ / 128, S_ / 128, NH * B_), 256, 0, stream>>>(
        probs_bf + (size_t)h0 * S_ * S_, (long)S_ * S_, (long)H_ * S_ * S_, S_,
        upT_post, 0, (long)F_ * S_, S_,
        pup_c, (long)F_, (long)S_ * ldK, ldK, S_, nullptr);
    // G4: part[s*2+b][q,f] (+)= pup_c[b][q,:] . vw_c[f,:]  over K=NH*F, split-K 2 (z=s*2+b)
    if (h0 == 0)
      gemm_bt<float, false, false, 2, true><<<dim3(F_ / 128, S_ / 128, 4), 256, 0, stream>>>(
          pup_c, (long)(ldK / 2), (long)S_ * ldK, ldK,
          vw_c, (long)(ldK / 2), 0, ldK,
          part, (long)2 * S_ * F_, (long)S_ * F_, F_, ldK / 2, nullptr);
    else
      gemm_bt<float, false, true, 2, true><<<dim3(F_ / 128, S_ / 128, 4), 256, 0, stream>>>(
          pup_c, (long)(ldK / 2), (long)S_ * ldK, ldK,
          vw_c, (long)(ldK / 2), 0, ldK,
          part, (long)2 * S_ * F_, (long)S_ * F_, F_, ldK / 2, nullptr);
  }
  const long n_out = (long)B_ * S_ * F_;
  k_reduce_out<<<(n_out / 4 + 255) / 256, 256, 0, stream>>>(part, out, n_out, 4);
}